// Round 10
// baseline (12824.225 us; speedup 1.0000x reference)
//
#include <hip/hip_runtime.h>
#include <math.h>

#define B_ 64
#define T_ 512
#define F_ 128
#define H_ 512
#define NBLK 384
#define SPIN_MAX (1 << 23)

typedef short bf16x8 __attribute__((ext_vector_type(8)));
typedef float f32x4 __attribute__((ext_vector_type(4)));
typedef int   i32x4 __attribute__((ext_vector_type(4)));

// Round-to-nearest bf16.
__device__ __forceinline__ unsigned short bf_rn(float f) {
    unsigned u = __float_as_uint(f);
    u += 0x7FFF + ((u >> 16) & 1);
    return (unsigned short)(u >> 16);
}

// Split fp32 -> packed (lo_bf16 << 16) | hi_bf16. hi RN, lo = RN(f - hi).
// Combined rel err ~2^-17. Done ONCE at produce time.
__device__ __forceinline__ unsigned packsplit(float f) {
    const unsigned short hi = bf_rn(f);
    const float lof = f - __uint_as_float((unsigned)hi << 16);
    return ((unsigned)bf_rn(lof) << 16) | hi;
}
__device__ __forceinline__ float unpacksplit(unsigned u) {
    return __uint_as_float(u << 16) + __uint_as_float(u & 0xFFFF0000u);
}

// ---------------------------------------------------------------------------
// One-time input transform: input[b][t][f] -> packed split-bf16
// xs[t][kstep=f>>5][b][f&31]  (B-operand stream layout).
// ---------------------------------------------------------------------------
__global__ void transpose_x(const float* __restrict__ in, unsigned* __restrict__ xs) {
    const int t = blockIdx.x;
    for (int idx = threadIdx.x; idx < B_ * F_; idx += blockDim.x) {
        const int bb = idx >> 7, f = idx & (F_ - 1);
        const float v = in[(size_t)bb * T_ * F_ + (size_t)t * F_ + f];
        xs[(size_t)t * 8192 + (f >> 5) * 2048 + bb * 32 + (f & 31)] = packsplit(v);
    }
}

__device__ __forceinline__ float sigmoid_(float x) { return 1.0f / (1.0f + expf(-x)); }

// Device-coherent ops (relaxed agent-scope atomics -> sc1 point-to-point).
__device__ __forceinline__ unsigned loadc_u32(const unsigned* p) {
    return __hip_atomic_load(p, __ATOMIC_RELAXED, __HIP_MEMORY_SCOPE_AGENT);
}
__device__ __forceinline__ unsigned long long loadc_u64(const unsigned* p) {
    return __hip_atomic_load((const unsigned long long*)p, __ATOMIC_RELAXED,
                             __HIP_MEMORY_SCOPE_AGENT);
}
__device__ __forceinline__ void storec_u32(unsigned* p, unsigned v) {
    __hip_atomic_store(p, v, __ATOMIC_RELAXED, __HIP_MEMORY_SCOPE_AGENT);
}
__device__ __forceinline__ void storec_f(float* p, float v) {
    __hip_atomic_store(p, v, __ATOMIC_RELAXED, __HIP_MEMORY_SCOPE_AGENT);
}
__device__ __forceinline__ float loadc_f(const float* p) {
    return __hip_atomic_load(p, __ATOMIC_RELAXED, __HIP_MEMORY_SCOPE_AGENT);
}

// ---------------------------------------------------------------------------
// Fence-free grid barrier with bounded spins (proven R6-R9).
// ---------------------------------------------------------------------------
__device__ __forceinline__ void gbar(int* __restrict__ slots, int* __restrict__ go,
                                     int bid, int tid, int e) {
    asm volatile("s_waitcnt vmcnt(0) lgkmcnt(0)" ::: "memory");
    __syncthreads();
    if (tid == 0)
        __hip_atomic_store(&slots[bid * 16], e, __ATOMIC_RELAXED,
                           __HIP_MEMORY_SCOPE_AGENT);
    if (bid == 0) {
        for (int s2 = tid; s2 < NBLK; s2 += 256) {
            int guard = 0;
            while (__hip_atomic_load(&slots[s2 * 16], __ATOMIC_RELAXED,
                                     __HIP_MEMORY_SCOPE_AGENT) < e &&
                   ++guard < SPIN_MAX)
                __builtin_amdgcn_s_sleep(1);
        }
        __syncthreads();
        if (tid == 0)
            __hip_atomic_store(go, e, __ATOMIC_RELAXED, __HIP_MEMORY_SCOPE_AGENT);
    } else if (tid == 0) {
        int guard = 0;
        while (__hip_atomic_load(go, __ATOMIC_RELAXED,
                                 __HIP_MEMORY_SCOPE_AGENT) < e &&
               ++guard < SPIN_MAX)
            __builtin_amdgcn_s_sleep(1);
    }
    __syncthreads();
}

// ---------------------------------------------------------------------------
// One step's GEMM: D[16 gate-rows][16 b] over K = [x-seg|h-seg].
// A = weights (split bf16) from LDS frag-order (conflict-free b128 reads).
// B = stream as packed split-bf16 dwords, [kstep][b][32] layout: lane reads
// 8 CONSECUTIVE dwords -> 4x u64 coherent loads (2x dwordx4 for layer-0 x).
// Unpack = 8 v_perm. 3 independent MFMA chains (hh, lh, hl). 8-deep pipeline.
// ---------------------------------------------------------------------------
template <int NKX, bool XCOH>
__device__ __forceinline__ void step_mfma(const unsigned* __restrict__ xs_l,
                                          const unsigned* __restrict__ hs_l,
                                          const unsigned short* wfrag,
                                          const int lane, f32x4 acc[3]) {
    constexpr int NK = NKX + 16;      // total ksteps (K/32)
    unsigned v[8][8];

    auto load8 = [&](unsigned* d, int i) {
        const unsigned* p = (i < NKX) ? (xs_l + (size_t)i * 2048)
                                      : (hs_l + (size_t)(i - NKX) * 2048);
        if ((i < NKX) ? XCOH : true) {
#pragma unroll
            for (int q = 0; q < 4; ++q) {
                const unsigned long long u = loadc_u64(p + 2 * q);
                d[2 * q]     = (unsigned)u;
                d[2 * q + 1] = (unsigned)(u >> 32);
            }
        } else {
            const uint4 q0 = *(const uint4*)p;
            const uint4 q1 = *(const uint4*)(p + 4);
            d[0] = q0.x; d[1] = q0.y; d[2] = q0.z; d[3] = q0.w;
            d[4] = q1.x; d[5] = q1.y; d[6] = q1.z; d[7] = q1.w;
        }
    };

#pragma unroll
    for (int p = 0; p < 8; ++p) load8(v[p], p);

#pragma unroll
    for (int i = 0; i < NK; ++i) {
        union Frag { i32x4 i4; bf16x8 s; } BH, BL, AH, AL;
        const unsigned* d = v[i % 8];
#pragma unroll
        for (int p2 = 0; p2 < 4; ++p2) {
            BH.i4[p2] = __builtin_amdgcn_perm(d[2 * p2 + 1], d[2 * p2], 0x05040100u);
            BL.i4[p2] = __builtin_amdgcn_perm(d[2 * p2 + 1], d[2 * p2], 0x07060302u);
        }
        if (i + 8 < NK) load8(v[i % 8], i + 8);
        AH.i4 = *(const i32x4*)&wfrag[i * 1024 + lane * 8];
        AL.i4 = *(const i32x4*)&wfrag[i * 1024 + 512 + lane * 8];
        acc[0] = __builtin_amdgcn_mfma_f32_16x16x32_bf16(AH.s, BH.s, acc[0], 0, 0, 0);
        acc[1] = __builtin_amdgcn_mfma_f32_16x16x32_bf16(AL.s, BH.s, acc[1], 0, 0, 0);
        acc[2] = __builtin_amdgcn_mfma_f32_16x16x32_bf16(AH.s, BL.s, acc[2], 0, 0, 0);
    }
}

// ---------------------------------------------------------------------------
// Persistent layer-pipelined LSTM scan, MFMA + packed split-bf16 stream.
// Block (layer=bid>>7, cb=bid&127) owns 16 gate-rows (cols c0..c0+3 x gates
// i,f,g,o). Wave w owns b-tile [16w,16w+16). Lane (n,q) finalizes
// (b=16w+n, col=c0+q) fully in-register; h stored packed split-bf16 in
// [parity][kstep][b][32] (next step's B layout, zero repack work).
// ---------------------------------------------------------------------------
__global__ void __launch_bounds__(256, 2) lstm_scan(
    const unsigned* __restrict__ xs, unsigned* __restrict__ hb,
    float* __restrict__ h1s, float* __restrict__ out,
    int* __restrict__ bar_slots, int* __restrict__ bar_go,
    const float* __restrict__ Wih0, const float* __restrict__ Whh0,
    const float* __restrict__ bih0, const float* __restrict__ bhh0,
    const float* __restrict__ Wih1, const float* __restrict__ Whh1,
    const float* __restrict__ bih1, const float* __restrict__ bhh1,
    const float* __restrict__ Wih2, const float* __restrict__ Whh2,
    const float* __restrict__ bih2, const float* __restrict__ bhh2,
    const float* __restrict__ fcW1, const float* __restrict__ fcb1,
    const float* __restrict__ fcW2, const float* __restrict__ fcb2) {
    __shared__ unsigned short wfrag[32 * 1024];   // [kstep][hi512|lo512], <=64 KB
    __shared__ float redsc[4 * 64];               // FC-head reduction only

    const float* WihA[3] = {Wih0, Wih1, Wih2};
    const float* WhhA[3] = {Whh0, Whh1, Whh2};
    const float* bihA[3] = {bih0, bih1, bih2};
    const float* bhhA[3] = {bhh0, bhh1, bhh2};

    const int tid   = threadIdx.x;
    const int bid   = blockIdx.x;
    const int layer = bid >> 7;
    const int cb    = bid & 127;
    const int c0    = cb * 4;
    const int lane  = tid & 63;
    const int w     = __builtin_amdgcn_readfirstlane(tid >> 6);
    const int KX    = (layer == 0) ? F_ : H_;
    const int NK    = KX / 32 + 16;

    const float* wih = WihA[layer];
    const float* whh = WhhA[layer];

    // ---- Stage weights once: split bf16 (RN both terms), A-frag order.
    for (int idx = tid; idx < NK * 512; idx += 256) {
        const int i = idx >> 9, rem = idx & 511;
        const int l = rem >> 3, j = rem & 7;
        const int m = l & 15;
        const int grow = (m & 3) * 512 + c0 + (m >> 2);
        const int k = i * 32 + (l >> 4) * 8 + j;
        const float f = (k < KX) ? wih[(size_t)grow * KX + k]
                                 : whh[(size_t)grow * 512 + (k - KX)];
        const unsigned short hi = bf_rn(f);
        const float lof = f - __uint_as_float((unsigned)hi << 16);
        wfrag[i * 1024 + l * 8 + j]       = hi;
        wfrag[i * 1024 + 512 + l * 8 + j] = bf_rn(lof);
    }
    __syncthreads();

    // Finalize-role constants: lane owns (b = 16w + n, col = c0 + q).
    const int fb    = w * 16 + (lane & 15);
    const int mycol = c0 + (lane >> 4);
    float bias[4];
#pragma unroll
    for (int g = 0; g < 4; ++g)
        bias[g] = bihA[layer][g * 512 + mycol] + bhhA[layer][g * 512 + mycol];

    // h buffers: [layer][parity][kstep 16][b 64][32] packed dwords.
    unsigned* hb_l = hb + (size_t)layer * 65536;
    const unsigned* hb_in = hb + (size_t)(layer - 1) * 65536;
    const int hidx = (mycol >> 5) * 2048 + fb * 32 + (mycol & 31);  // store slot

    float c_reg = 0.0f;
    const int laneoff = (w * 16 + (lane & 15)) * 32 + (lane >> 4) * 8;

    for (int s = 0; s < T_ + 2; ++s) {
        const int t = s - layer;
        if (t >= 0 && t < T_) {
            const int p_out  = t & 1;
            const int p_prev = (t + 1) & 1;
            const unsigned* xs_l =
                ((layer == 0) ? (xs + (size_t)t * 8192)
                              : (hb_in + (size_t)p_out * 32768)) + laneoff;
            const unsigned* hs_l = hb_l + (size_t)p_prev * 32768 + laneoff;

            f32x4 acc[3] = {{0.f,0.f,0.f,0.f},{0.f,0.f,0.f,0.f},{0.f,0.f,0.f,0.f}};
            if (layer == 0) step_mfma<4, false>(xs_l, hs_l, wfrag, lane, acc);
            else            step_mfma<16, true>(xs_l, hs_l, wfrag, lane, acc);

            // In-register finalize: reg g = gate g of (fb, mycol).
            float a[4];
#pragma unroll
            for (int g = 0; g < 4; ++g)
                a[g] = bias[g] + acc[0][g] + acc[1][g] + acc[2][g];

            const float ig = sigmoid_(a[0]);
            const float fg = sigmoid_(a[1]);
            const float gg = tanhf(a[2]);
            const float og = sigmoid_(a[3]);
            c_reg = fg * c_reg + ig * gg;
            const float hv = og * tanhf(c_reg);
            storec_u32(&hb_l[(size_t)p_out * 32768 + hidx], packsplit(hv));
        }
        gbar(bar_slots, bar_go, bid, tid, s + 1);
    }

    // ---- FC head. h2 = layer-2 h at t=511 (parity 1), packed layout.
    const unsigned* h2u = hb + (size_t)2 * 65536 + 32768;
    const int fcb = tid & 63;
    if (bid < 64) {
        float part = 0.0f;
        const float* wrow = fcW1 + (size_t)bid * H_ + w * 128;
#pragma unroll 8
        for (int k = 0; k < 128; ++k) {
            const int kk = w * 128 + k;
            const unsigned u = loadc_u32(
                h2u + (kk >> 5) * 2048 + fcb * 32 + (kk & 31));
            part = fmaf(wrow[k], unpacksplit(u), part);
        }
        redsc[w * 64 + fcb] = part;
        __syncthreads();
        if (tid < 64) {
            float acc2 = fcb1[bid] + redsc[tid] + redsc[64 + tid] +
                         redsc[128 + tid] + redsc[192 + tid];
            storec_f(&h1s[bid * B_ + tid], fmaxf(acc2, 0.0f));
        }
    }
    gbar(bar_slots, bar_go, bid, tid, T_ + 3);
    if (bid == 0 && tid < 64) {
        float acc2 = fcb2[0];
#pragma unroll
        for (int c = 0; c < 64; ++c)
            acc2 = fmaf(fcW2[c], loadc_f(&h1s[c * B_ + tid]), acc2);
        out[tid] = fmaxf(acc2, 0.0f);
    }
}

// ---------------------------------------------------------------------------
extern "C" void kernel_launch(void* const* d_in, const int* in_sizes, int n_in,
                              void* d_out, int out_size, void* d_ws, size_t ws_size,
                              hipStream_t stream) {
    const float* in    = (const float*)d_in[0];
    const float* Wih0  = (const float*)d_in[1];
    const float* Whh0  = (const float*)d_in[2];
    const float* bih0  = (const float*)d_in[3];
    const float* bhh0  = (const float*)d_in[4];
    const float* Wih1  = (const float*)d_in[5];
    const float* Whh1  = (const float*)d_in[6];
    const float* bih1  = (const float*)d_in[7];
    const float* bhh1  = (const float*)d_in[8];
    const float* Wih2  = (const float*)d_in[9];
    const float* Whh2  = (const float*)d_in[10];
    const float* bih2  = (const float*)d_in[11];
    const float* bhh2  = (const float*)d_in[12];
    const float* fcW1  = (const float*)d_in[13];
    const float* fcb1  = (const float*)d_in[14];
    const float* fcW2  = (const float*)d_in[15];
    const float* fcb2  = (const float*)d_in[16];
    float* outp = (float*)d_out;

    unsigned* xs  = (unsigned*)d_ws;                   // [T][4][64][32]  16 MB
    unsigned* hbf = xs + (size_t)T_ * 8192;            // [3][2][16][64][32] 768 KB
    float*    h1s = (float*)(hbf + (size_t)3 * 65536); // [64][64]         16 KB
    int*      bar = (int*)(h1s + 64 * 64);
    int*      bar_slots = bar;                         // NBLK*16 ints
    int*      bar_go    = bar + NBLK * 16;             // 1 int

    hipMemsetAsync(hbf, 0,
                   ((size_t)3 * 65536 + 64 * 64 + NBLK * 16 + 16) * sizeof(int),
                   stream);

    transpose_x<<<dim3(T_), dim3(256), 0, stream>>>(in, xs);

    void* args[] = {
        (void*)&xs, (void*)&hbf, (void*)&h1s, (void*)&outp,
        (void*)&bar_slots, (void*)&bar_go,
        (void*)&Wih0, (void*)&Whh0, (void*)&bih0, (void*)&bhh0,
        (void*)&Wih1, (void*)&Whh1, (void*)&bih1, (void*)&bhh1,
        (void*)&Wih2, (void*)&Whh2, (void*)&bih2, (void*)&bhh2,
        (void*)&fcW1, (void*)&fcb1, (void*)&fcW2, (void*)&fcb2};
    hipLaunchCooperativeKernel((void*)lstm_scan, dim3(NBLK), dim3(256), args, 0, stream);
}

// Round 11
// 4413.632 us; speedup vs baseline: 2.9056x; 2.9056x over previous
//
#include <hip/hip_runtime.h>
#include <math.h>

#define B_ 64
#define T_ 512
#define F_ 128
#define H_ 512
#define NBLK 384
#define SPIN_MAX (1 << 23)

typedef short bf16x8 __attribute__((ext_vector_type(8)));
typedef float f32x4 __attribute__((ext_vector_type(4)));
typedef int   i32x4 __attribute__((ext_vector_type(4)));

// Round-to-nearest bf16.
__device__ __forceinline__ unsigned short bf_rn(float f) {
    unsigned u = __float_as_uint(f);
    u += 0x7FFF + ((u >> 16) & 1);
    return (unsigned short)(u >> 16);
}

// fp32 -> packed (lo_bf16 << 16) | hi_bf16 (hi RN, lo = RN(residual)).
__device__ __forceinline__ unsigned packsplit(float f) {
    const unsigned short hi = bf_rn(f);
    const float lof = f - __uint_as_float((unsigned)hi << 16);
    return ((unsigned)bf_rn(lof) << 16) | hi;
}

// ---------------------------------------------------------------------------
// One-time input transform: input[b][t][f] -> interleaved kpair stream
// xs[t][kpair=f>>1][b][{hiD,loD}]; hiD = hi(k even)|hi(k odd)<<16, loD same
// for lo-split. Write = coalesced u64 per (kpair,b).
// ---------------------------------------------------------------------------
__global__ void transpose_x(const float* __restrict__ in, unsigned* __restrict__ xs) {
    const int t = blockIdx.x;
    for (int idx = threadIdx.x; idx < B_ * F_ / 2; idx += blockDim.x) {
        const int kp = idx >> 6;        // 0..63
        const int bb = idx & 63;
        const float v0 = in[(size_t)bb * T_ * F_ + (size_t)t * F_ + 2 * kp];
        const float v1 = in[(size_t)bb * T_ * F_ + (size_t)t * F_ + 2 * kp + 1];
        const unsigned P0 = packsplit(v0), P1 = packsplit(v1);
        const unsigned hiD = __builtin_amdgcn_perm(P1, P0, 0x05040100u);
        const unsigned loD = __builtin_amdgcn_perm(P1, P0, 0x07060302u);
        unsigned* dst = xs + (size_t)t * 8192 + (size_t)kp * 128 + bb * 2;
        dst[0] = hiD; dst[1] = loD;
    }
}

__device__ __forceinline__ float sigmoid_(float x) { return 1.0f / (1.0f + expf(-x)); }

// Device-coherent ops (relaxed agent-scope atomics -> sc1 point-to-point).
__device__ __forceinline__ unsigned long long loadc_u64(const unsigned* p) {
    return __hip_atomic_load((const unsigned long long*)p, __ATOMIC_RELAXED,
                             __HIP_MEMORY_SCOPE_AGENT);
}
__device__ __forceinline__ void storec_u64(unsigned* p, unsigned long long v) {
    __hip_atomic_store((unsigned long long*)p, v, __ATOMIC_RELAXED,
                       __HIP_MEMORY_SCOPE_AGENT);
}
__device__ __forceinline__ void storec_f(float* p, float v) {
    __hip_atomic_store(p, v, __ATOMIC_RELAXED, __HIP_MEMORY_SCOPE_AGENT);
}
__device__ __forceinline__ float loadc_f(const float* p) {
    return __hip_atomic_load(p, __ATOMIC_RELAXED, __HIP_MEMORY_SCOPE_AGENT);
}

// ---------------------------------------------------------------------------
// Fence-free grid barrier with bounded spins (proven R6-R10).
// ---------------------------------------------------------------------------
__device__ __forceinline__ void gbar(int* __restrict__ slots, int* __restrict__ go,
                                     int bid, int tid, int e) {
    asm volatile("s_waitcnt vmcnt(0) lgkmcnt(0)" ::: "memory");
    __syncthreads();
    if (tid == 0)
        __hip_atomic_store(&slots[bid * 16], e, __ATOMIC_RELAXED,
                           __HIP_MEMORY_SCOPE_AGENT);
    if (bid == 0) {
        for (int s2 = tid; s2 < NBLK; s2 += 256) {
            int guard = 0;
            while (__hip_atomic_load(&slots[s2 * 16], __ATOMIC_RELAXED,
                                     __HIP_MEMORY_SCOPE_AGENT) < e &&
                   ++guard < SPIN_MAX)
                __builtin_amdgcn_s_sleep(1);
        }
        __syncthreads();
        if (tid == 0)
            __hip_atomic_store(go, e, __ATOMIC_RELAXED, __HIP_MEMORY_SCOPE_AGENT);
    } else if (tid == 0) {
        int guard = 0;
        while (__hip_atomic_load(go, __ATOMIC_RELAXED,
                                 __HIP_MEMORY_SCOPE_AGENT) < e &&
               ++guard < SPIN_MAX)
            __builtin_amdgcn_s_sleep(1);
    }
    __syncthreads();
}

// ---------------------------------------------------------------------------
// One step's GEMM: D[16 gate-rows][16 b] over K = [x-seg|h-seg].
// A = weights (split bf16) from LDS frag-order (conflict-free b128).
// B = interleaved kpair stream: lane (b=16w+n, oct=lane>>4) loads 4 u64 per
// kstep at dword (kstep*2048 + oct*512 + p2*128 + b*2) -> {hiD,loD} pairs.
// BH/BL fragments are register selection, ZERO pack VALU.
// 3 independent MFMA chains (hh, lh, hl). 8-deep pipeline.
// ---------------------------------------------------------------------------
template <int NKX, bool XCOH>
__device__ __forceinline__ void step_mfma(const unsigned* __restrict__ xs_l,
                                          const unsigned* __restrict__ hs_l,
                                          const unsigned short* wfrag,
                                          const int lane, f32x4 acc[3]) {
    constexpr int NK = NKX + 16;      // total ksteps (K/32)
    unsigned long long v[8][4];       // [pipe][p2] = {hiD, loD}

    auto load4 = [&](unsigned long long* d, int i) {
        const unsigned* p = (i < NKX) ? (xs_l + (size_t)i * 2048)
                                      : (hs_l + (size_t)(i - NKX) * 2048);
        if ((i < NKX) ? XCOH : true) {
#pragma unroll
            for (int q = 0; q < 4; ++q) d[q] = loadc_u64(p + q * 128);
        } else {
#pragma unroll
            for (int q = 0; q < 4; ++q) d[q] = *(const unsigned long long*)(p + q * 128);
        }
    };

#pragma unroll
    for (int p = 0; p < 8; ++p) load4(v[p], p);

#pragma unroll
    for (int i = 0; i < NK; ++i) {
        union Frag { i32x4 i4; bf16x8 s; } BH, BL, AH, AL;
        const unsigned long long* d = v[i % 8];
#pragma unroll
        for (int p2 = 0; p2 < 4; ++p2) {
            BH.i4[p2] = (int)(unsigned)d[p2];          // hiD(kpair p2)
            BL.i4[p2] = (int)(unsigned)(d[p2] >> 32);  // loD(kpair p2)
        }
        if (i + 8 < NK) load4(v[i % 8], i + 8);
        AH.i4 = *(const i32x4*)&wfrag[i * 1024 + lane * 8];
        AL.i4 = *(const i32x4*)&wfrag[i * 1024 + 512 + lane * 8];
        acc[0] = __builtin_amdgcn_mfma_f32_16x16x32_bf16(AH.s, BH.s, acc[0], 0, 0, 0);
        acc[1] = __builtin_amdgcn_mfma_f32_16x16x32_bf16(AL.s, BH.s, acc[1], 0, 0, 0);
        acc[2] = __builtin_amdgcn_mfma_f32_16x16x32_bf16(AH.s, BL.s, acc[2], 0, 0, 0);
    }
}

// ---------------------------------------------------------------------------
// Persistent layer-pipelined LSTM scan. Block (layer=bid>>7, cb) owns 16
// gate-rows (cols c0..c0+3 x gates i,f,g,o); wave w owns b-tile [16w,16w+16).
// Lane (n,q) finalizes (b=16w+n, col=c0+q) in-register; h written as
// interleaved kpair stream (next step's B layout): lane pairs cols via
// shfl_xor(16), even-q lanes store one coherent u64 {hiD,loD}.
// ---------------------------------------------------------------------------
__global__ void __launch_bounds__(256, 2) lstm_scan(
    const unsigned* __restrict__ xs, unsigned* __restrict__ hb,
    float* __restrict__ h1s, float* __restrict__ out,
    int* __restrict__ bar_slots, int* __restrict__ bar_go,
    const float* __restrict__ Wih0, const float* __restrict__ Whh0,
    const float* __restrict__ bih0, const float* __restrict__ bhh0,
    const float* __restrict__ Wih1, const float* __restrict__ Whh1,
    const float* __restrict__ bih1, const float* __restrict__ bhh1,
    const float* __restrict__ Wih2, const float* __restrict__ Whh2,
    const float* __restrict__ bih2, const float* __restrict__ bhh2,
    const float* __restrict__ fcW1, const float* __restrict__ fcb1,
    const float* __restrict__ fcW2, const float* __restrict__ fcb2) {
    __shared__ unsigned short wfrag[32 * 1024];   // [kstep][hi512|lo512], <=64 KB
    __shared__ float redsc[4 * 64];               // FC-head reduction only

    const float* WihA[3] = {Wih0, Wih1, Wih2};
    const float* WhhA[3] = {Whh0, Whh1, Whh2};
    const float* bihA[3] = {bih0, bih1, bih2};
    const float* bhhA[3] = {bhh0, bhh1, bhh2};

    const int tid   = threadIdx.x;
    const int bid   = blockIdx.x;
    const int layer = bid >> 7;
    const int cb    = bid & 127;
    const int c0    = cb * 4;
    const int lane  = tid & 63;
    const int w     = __builtin_amdgcn_readfirstlane(tid >> 6);
    const int KX    = (layer == 0) ? F_ : H_;
    const int NK    = KX / 32 + 16;

    const float* wih = WihA[layer];
    const float* whh = WhhA[layer];

    // ---- Stage weights once: split bf16 (RN both terms), A-frag order.
    for (int idx = tid; idx < NK * 512; idx += 256) {
        const int i = idx >> 9, rem = idx & 511;
        const int l = rem >> 3, j = rem & 7;
        const int m = l & 15;
        const int grow = (m & 3) * 512 + c0 + (m >> 2);
        const int k = i * 32 + (l >> 4) * 8 + j;
        const float f = (k < KX) ? wih[(size_t)grow * KX + k]
                                 : whh[(size_t)grow * 512 + (k - KX)];
        const unsigned short hi = bf_rn(f);
        const float lof = f - __uint_as_float((unsigned)hi << 16);
        wfrag[i * 1024 + l * 8 + j]       = hi;
        wfrag[i * 1024 + 512 + l * 8 + j] = bf_rn(lof);
    }
    __syncthreads();

    // Finalize-role constants: lane owns (b = 16w + n, col = c0 + q).
    const int fb    = w * 16 + (lane & 15);
    const int q     = lane >> 4;
    const int mycol = c0 + q;
    float bias[4];
#pragma unroll
    for (int g = 0; g < 4; ++g)
        bias[g] = bihA[layer][g * 512 + mycol] + bhhA[layer][g * 512 + mycol];

    // h buffers: [layer][parity][kpair 256][b 64][{hiD,loD}] dwords.
    unsigned* hb_l = hb + (size_t)layer * 65536;
    const unsigned* hb_in = hb + (size_t)(layer - 1) * 65536;
    // This lane-pair's store slot (even-q lanes store): kpair = mycol>>1.
    const int hstore = (mycol >> 1) * 128 + fb * 2;

    float c_reg = 0.0f;
    const int laneoff = q * 512 + fb * 2;   // oct=q: consumer base offset (dwords)

    for (int s = 0; s < T_ + 2; ++s) {
        const int t = s - layer;
        if (t >= 0 && t < T_) {
            const int p_out  = t & 1;
            const int p_prev = (t + 1) & 1;
            const unsigned* xs_l =
                ((layer == 0) ? (xs + (size_t)t * 8192)
                              : (hb_in + (size_t)p_out * 32768)) + laneoff;
            const unsigned* hs_l = hb_l + (size_t)p_prev * 32768 + laneoff;

            f32x4 acc[3] = {{0.f,0.f,0.f,0.f},{0.f,0.f,0.f,0.f},{0.f,0.f,0.f,0.f}};
            if (layer == 0) step_mfma<4, false>(xs_l, hs_l, wfrag, lane, acc);
            else            step_mfma<16, true>(xs_l, hs_l, wfrag, lane, acc);

            // In-register finalize: reg g = gate g of (fb, mycol).
            float a[4];
#pragma unroll
            for (int g = 0; g < 4; ++g)
                a[g] = bias[g] + acc[0][g] + acc[1][g] + acc[2][g];

            const float ig = sigmoid_(a[0]);
            const float fg = sigmoid_(a[1]);
            const float gg = tanhf(a[2]);
            const float og = sigmoid_(a[3]);
            c_reg = fg * c_reg + ig * gg;
            const float hv = og * tanhf(c_reg);

            // Pair columns (q, q^1) via shfl_xor(16); even-q lane stores u64.
            const unsigned P0 = packsplit(hv);
            const unsigned P1 = (unsigned)__shfl_xor((int)P0, 16, 64);
            if ((q & 1) == 0) {
                const unsigned hiD = __builtin_amdgcn_perm(P1, P0, 0x05040100u);
                const unsigned loD = __builtin_amdgcn_perm(P1, P0, 0x07060302u);
                storec_u64(&hb_l[(size_t)p_out * 32768 + hstore],
                           ((unsigned long long)loD << 32) | hiD);
            }
        }
        gbar(bar_slots, bar_go, bid, tid, s + 1);
    }

    // ---- FC head. h2 = layer-2 h at t=511 (parity 1), interleaved layout.
    const unsigned* h2u = hb + (size_t)2 * 65536 + 32768;
    const int fcb = tid & 63;
    if (bid < 64) {
        float part = 0.0f;
        const float* wrow = fcW1 + (size_t)bid * H_ + w * 128;
#pragma unroll 8
        for (int k = 0; k < 128; ++k) {
            const int kk = w * 128 + k;
            const unsigned long long d =
                loadc_u64(h2u + (kk >> 1) * 128 + fcb * 2);
            const unsigned hiD = (unsigned)d, loD = (unsigned)(d >> 32);
            const int sh = (kk & 1) * 16;
            const float val =
                __uint_as_float(((hiD >> sh) & 0xFFFFu) << 16) +
                __uint_as_float(((loD >> sh) & 0xFFFFu) << 16);
            part = fmaf(wrow[k], val, part);
        }
        redsc[w * 64 + fcb] = part;
        __syncthreads();
        if (tid < 64) {
            float acc2 = fcb1[bid] + redsc[tid] + redsc[64 + tid] +
                         redsc[128 + tid] + redsc[192 + tid];
            storec_f(&h1s[bid * B_ + tid], fmaxf(acc2, 0.0f));
        }
    }
    gbar(bar_slots, bar_go, bid, tid, T_ + 3);
    if (bid == 0 && tid < 64) {
        float acc2 = fcb2[0];
#pragma unroll
        for (int c = 0; c < 64; ++c)
            acc2 = fmaf(fcW2[c], loadc_f(&h1s[c * B_ + tid]), acc2);
        out[tid] = fmaxf(acc2, 0.0f);
    }
}

// ---------------------------------------------------------------------------
extern "C" void kernel_launch(void* const* d_in, const int* in_sizes, int n_in,
                              void* d_out, int out_size, void* d_ws, size_t ws_size,
                              hipStream_t stream) {
    const float* in    = (const float*)d_in[0];
    const float* Wih0  = (const float*)d_in[1];
    const float* Whh0  = (const float*)d_in[2];
    const float* bih0  = (const float*)d_in[3];
    const float* bhh0  = (const float*)d_in[4];
    const float* Wih1  = (const float*)d_in[5];
    const float* Whh1  = (const float*)d_in[6];
    const float* bih1  = (const float*)d_in[7];
    const float* bhh1  = (const float*)d_in[8];
    const float* Wih2  = (const float*)d_in[9];
    const float* Whh2  = (const float*)d_in[10];
    const float* bih2  = (const float*)d_in[11];
    const float* bhh2  = (const float*)d_in[12];
    const float* fcW1  = (const float*)d_in[13];
    const float* fcb1  = (const float*)d_in[14];
    const float* fcW2  = (const float*)d_in[15];
    const float* fcb2  = (const float*)d_in[16];
    float* outp = (float*)d_out;

    unsigned* xs  = (unsigned*)d_ws;                   // [T][8192]       16 MB
    unsigned* hbf = xs + (size_t)T_ * 8192;            // [3][2][32768]  768 KB
    float*    h1s = (float*)(hbf + (size_t)3 * 65536); // [64][64]        16 KB
    int*      bar = (int*)(h1s + 64 * 64);
    int*      bar_slots = bar;                         // NBLK*16 ints
    int*      bar_go    = bar + NBLK * 16;             // 1 int

    hipMemsetAsync(hbf, 0,
                   ((size_t)3 * 65536 + 64 * 64 + NBLK * 16 + 16) * sizeof(int),
                   stream);

    transpose_x<<<dim3(T_), dim3(256), 0, stream>>>(in, xs);

    void* args[] = {
        (void*)&xs, (void*)&hbf, (void*)&h1s, (void*)&outp,
        (void*)&bar_slots, (void*)&bar_go,
        (void*)&Wih0, (void*)&Whh0, (void*)&bih0, (void*)&bhh0,
        (void*)&Wih1, (void*)&Whh1, (void*)&bih1, (void*)&bhh1,
        (void*)&Wih2, (void*)&Whh2, (void*)&bih2, (void*)&bhh2,
        (void*)&fcW1, (void*)&fcb1, (void*)&fcW2, (void*)&fcb2};
    hipLaunchCooperativeKernel((void*)lstm_scan, dim3(NBLK), dim3(256), args, 0, stream);
}